// Round 12
// baseline (1447.271 us; speedup 1.0000x reference)
//
#include <hip/hip_runtime.h>
#include <hip/hip_bf16.h>

#define GG 128
#define G2 (GG*GG)
#define CC 256
#define HH 4
#define NPTS 100000
#define NB 2
#define LN_EPS 1e-5f

typedef __attribute__((ext_vector_type(8))) short short8v;
typedef __attribute__((ext_vector_type(4))) float float4v;

// ---- bf16 helpers (RNE round, bit-level) ----
__device__ __forceinline__ unsigned short bfround(float x){
    unsigned u = __float_as_uint(x);
    return (unsigned short)((u + 0x7FFFu + ((u >> 16) & 1u)) >> 16);
}
__device__ __forceinline__ float bfval(unsigned short h){
    return __uint_as_float(((unsigned)h) << 16);
}

// B2[n][k] bf16, n in [0,512): n<256 -> Wk row n, else Wv row n-256.
// k in [0,256): w_hi ; [256,512): w_lo ; [512,768): w_hi (pairs A''=[hi|hi|lo])
__global__ __launch_bounds__(256) void prep_b2_kernel(
    const float* __restrict__ Wk, const float* __restrict__ Wv,
    const float* __restrict__ kb, const float* __restrict__ vb,
    unsigned short* __restrict__ B2, float* __restrict__ bias_comb)
{
    int n = blockIdx.x;
    int t = threadIdx.x;
    const float* src = (n < 256) ? (Wk + (size_t)n*CC) : (Wv + (size_t)(n-256)*CC);
    float w = src[t];
    unsigned short h = bfround(w);
    unsigned short l = bfround(w - bfval(h));
    unsigned short* row = B2 + (size_t)n*768;
    row[t] = h;
    row[256 + t] = l;
    row[512 + t] = h;
    if (t == 0) bias_comb[n] = (n < 256) ? kb[n] : vb[n-256];
}

// q (C, G2)  ->  qT[plane][cell][c]
__global__ __launch_bounds__(256) void transpose_q_kernel(
    const float* __restrict__ qxy, const float* __restrict__ qxz,
    const float* __restrict__ qyz, float* __restrict__ qT)
{
    int blk = blockIdx.x;
    int plane = blk >> 10;
    int rem = blk & 1023;
    int cell0 = (rem >> 2) << 6;
    int c0 = (rem & 3) << 6;
    const float* q = plane == 0 ? qxy : (plane == 1 ? qxz : qyz);
    __shared__ float tile[64][65];
    int tx = threadIdx.x & 63;
    int ty = threadIdx.x >> 6;
    #pragma unroll
    for (int i = ty; i < 64; i += 4)
        tile[i][tx] = q[(size_t)(c0 + i)*G2 + cell0 + tx];
    __syncthreads();
    #pragma unroll
    for (int i = ty; i < 64; i += 4)
        qT[((size_t)plane*G2 + cell0 + i)*CC + c0 + tx] = tile[tx][i];
}

// Fused: coords + LN + split-bf16 MFMA K&V GEMM + lane-parallel s epilogue.
// 32 points/block, 4 waves. K_f32 aliases the dead A region (LDS 34.2 KB).
// R12: NO atomicMax — segment max moved to gather's prepass.
__global__ __launch_bounds__(256, 4) void point_kernel(
    const float* __restrict__ feats, const float* __restrict__ bounds,
    const unsigned short* __restrict__ B2, const float* __restrict__ bias_comb,
    const float* __restrict__ lng, const float* __restrict__ lnb,
    const float* __restrict__ qT,
    unsigned short* __restrict__ Vout, float* __restrict__ s_out,
    int* __restrict__ cnt)
{
    // phase A (stages 1-2): Ahi[32][264] @0 (16896 B), Alo[32][264] @16896
    // phase B (stage 3):    K_f32[32][260] @0 (33280 B)  -- aliases A
    // coords[96] @33792 (384 B), live across both phases
    __shared__ __align__(16) char lraw[34176];
    unsigned short* Ahi = (unsigned short*)lraw;
    unsigned short* Alo = (unsigned short*)(lraw + 16896);
    float* K_f = (float*)lraw;
    float* coords_lds = (float*)(lraw + 33792);

    int t = threadIdx.x;
    int lane = t & 63;
    int w = t >> 6;
    long long g0 = (long long)blockIdx.x * 32;               // 32 | NPTS
    int b  = (int)(g0 / NPTS);
    int pt0 = (int)(g0 % NPTS);

    // ---- stage 1: preload feats (all 8 points, one latency exposure) ----
    float xr[8][4];
    #pragma unroll
    for (int r = 0; r < 8; r++){
        int p = w*8 + r;
        const float* f = feats + ((size_t)b*NPTS + pt0 + p)*CC;
        xr[r][0] = f[lane];
        xr[r][1] = f[lane + 64];
        xr[r][2] = f[lane + 128];
        xr[r][3] = f[lane + 192];
    }

    // ---- coords + LayerNorm + bf16 hi/lo pack (bit-exact R10 order) ----
    float lg0 = lng[lane], lg1 = lng[lane+64], lg2 = lng[lane+128], lg3 = lng[lane+192];
    float lb0 = lnb[lane], lb1 = lnb[lane+64], lb2 = lnb[lane+128], lb3 = lnb[lane+192];
    #pragma unroll
    for (int r = 0; r < 8; r++){
        int p = w*8 + r;
        float x0 = xr[r][0], x1 = xr[r][1], x2 = xr[r][2], x3 = xr[r][3];
        if (lane < 3){
            float l0 = bounds[2*lane], h0 = bounds[2*lane+1];
            float tnum = __fmul_rn(2.0f, __fsub_rn(x0, l0));
            float cv = __fsub_rn(__fdiv_rn(tnum, __fsub_rn(h0, l0)), 1.0f);
            x0 = cv;
            coords_lds[p*3 + lane] = cv;
        }
        float s1 = x0 + x1 + x2 + x3;
        float s2 = x0*x0 + x1*x1 + x2*x2 + x3*x3;
        #pragma unroll
        for (int off = 32; off; off >>= 1){
            s1 += __shfl_xor(s1, off);
            s2 += __shfl_xor(s2, off);
        }
        float mu = s1 * (1.0f/CC);
        float var = s2 * (1.0f/CC) - mu*mu;
        float rs = rsqrtf(var + LN_EPS);

        float f0 = (x0 - mu)*rs*lg0 + lb0;
        float f1 = (x1 - mu)*rs*lg1 + lb1;
        float f2 = (x2 - mu)*rs*lg2 + lb2;
        float f3 = (x3 - mu)*rs*lg3 + lb3;
        unsigned short h0 = bfround(f0), h1 = bfround(f1);
        unsigned short h2 = bfround(f2), h3 = bfround(f3);
        Ahi[p*264 + lane      ] = h0;  Alo[p*264 + lane      ] = bfround(f0 - bfval(h0));
        Ahi[p*264 + lane +  64] = h1;  Alo[p*264 + lane +  64] = bfround(f1 - bfval(h1));
        Ahi[p*264 + lane + 128] = h2;  Alo[p*264 + lane + 128] = bfround(f2 - bfval(h2));
        Ahi[p*264 + lane + 192] = h3;  Alo[p*264 + lane + 192] = bfround(f3 - bfval(h3));
    }
    __syncthreads();

    // ---- stage 2: MFMA GEMM M=32 x N=128/wave x K=768 (hi*hi+hi*lo+lo*hi) ----
    {
        int apt = lane & 15;            // A row (point) within m-frag
        int krow = (lane >> 4) * 8;     // k sub-slot
        int n0 = w * 128;
        int bcol = n0 + (lane & 15);    // B row (n index)
        float4v acc0[8], acc1[8];       // m-frag 0 (pts 0-15), 1 (pts 16-31)
        #pragma unroll
        for (int ni = 0; ni < 8; ni++){
            float bz = bias_comb[n0 + ni*16 + (lane & 15)];
            acc0[ni][0]=bz; acc0[ni][1]=bz; acc0[ni][2]=bz; acc0[ni][3]=bz;
            acc1[ni][0]=bz; acc1[ni][1]=bz; acc1[ni][2]=bz; acc1[ni][3]=bz;
        }
        #pragma unroll 2
        for (int ks = 0; ks < 24; ks++){
            int term = ks >> 3;
            int kk = (ks & 7)*32 + krow;          // 0..255
            int kglob = term*256 + kk;            // 0..767
            const unsigned short* Abase = (term < 2) ? Ahi : Alo;
            short8v a0 = *reinterpret_cast<const short8v*>(Abase + apt*264 + kk);
            short8v a1 = *reinterpret_cast<const short8v*>(Abase + (16+apt)*264 + kk);
            #pragma unroll
            for (int ni = 0; ni < 8; ni++){
                short8v bf = *reinterpret_cast<const short8v*>(
                    B2 + (size_t)(bcol + ni*16)*768 + kglob);
                acc0[ni] = __builtin_amdgcn_mfma_f32_16x16x32_bf16(a0, bf, acc0[ni], 0, 0, 0);
                acc1[ni] = __builtin_amdgcn_mfma_f32_16x16x32_bf16(a1, bf, acc1[ni], 0, 0, 0);
            }
        }
        __syncthreads();   // all A reads complete; K may now alias A
        // epilogue: C/D layout col=lane&15, row=(lane>>4)*4+reg (R7-proven)
        if (w < 2){
            #pragma unroll
            for (int ni = 0; ni < 8; ni++){
                int ch = n0 + ni*16 + (lane & 15);
                #pragma unroll
                for (int r4 = 0; r4 < 4; r4++){
                    int pt = (lane >> 4)*4 + r4;
                    K_f[pt*260 + ch]        = acc0[ni][r4];
                    K_f[(16 + pt)*260 + ch] = acc1[ni][r4];
                }
            }
        } else {
            #pragma unroll
            for (int ni = 0; ni < 8; ni++){
                int ch = (n0 - 256) + ni*16 + (lane & 15);
                #pragma unroll
                for (int r4 = 0; r4 < 4; r4++){
                    int pt = (lane >> 4)*4 + r4;
                    Vout[((size_t)b*NPTS + pt0 + pt)*CC + ch]        = bfround(acc0[ni][r4]);
                    Vout[((size_t)b*NPTS + pt0 + 16 + pt)*CC + ch]   = bfround(acc1[ni][r4]);
                }
            }
        }
    }
    __syncthreads();

    // ---- stage 3: lane-parallel s + counts (NO atomicMax) ----
    // 64 lanes = 8 points x 8 channel-segments (32 ch each).
    {
        int grp = lane >> 3;           // point within wave's 8
        int g   = lane & 7;            // segment: channels [g*32, g*32+32)
        int h   = g >> 1;              // head (two segments per head)
        int p   = w*8 + grp;
        int pt  = pt0 + p;
        float cx = coords_lds[p*3], cy = coords_lds[p*3+1], cz = coords_lds[p*3+2];

        float4 k4[8];
        {
            const float4* Krow = reinterpret_cast<const float4*>(&K_f[p*260 + g*32]);
            #pragma unroll
            for (int j = 0; j < 8; j++) k4[j] = Krow[j];
        }
        // hoist all 3 cells (bit-exact chain) so q loads can overlap FMAs
        int cells[3];
        #pragma unroll
        for (int pl = 0; pl < 3; pl++){
            float a = (pl == 2) ? cy : cx;
            float bb = (pl == 0) ? cy : cz;
            float ua = __fmul_rn(__fadd_rn(__fmul_rn(a, 0.5f), 0.5f), (float)(GG-1));
            float ub = __fmul_rn(__fadd_rn(__fmul_rn(bb,0.5f), 0.5f), (float)(GG-1));
            int gx = (int)ua; gx = gx < 0 ? 0 : (gx > GG-1 ? GG-1 : gx);
            int gy = (int)ub; gy = gy < 0 ? 0 : (gy > GG-1 ? GG-1 : gy);
            cells[pl] = gx*GG + gy;
        }
        #pragma unroll
        for (int pl = 0; pl < 3; pl++){
            int cell = cells[pl];
            const float4* qrow = reinterpret_cast<const float4*>(
                qT + ((size_t)pl*G2 + cell)*CC + g*32);
            float a0 = 0.f, a1 = 0.f, a2 = 0.f, a3 = 0.f;
            #pragma unroll
            for (int j = 0; j < 8; j++){
                float4 q4 = qrow[j];
                a0 = fmaf(k4[j].x, q4.x, a0);
                a1 = fmaf(k4[j].y, q4.y, a1);
                a2 = fmaf(k4[j].z, q4.z, a2);
                a3 = fmaf(k4[j].w, q4.w, a3);
            }
            float sh = (a0 + a1) + (a2 + a3);
            sh += __shfl_xor(sh, 1);     // combine the head's two halves
            if ((lane & 1) == 0){
                int bp = b*3 + pl;
                s_out[((size_t)bp*NPTS + pt)*HH + h] = sh;
                if (g == 0) atomicAdd(&cnt[(size_t)bp*G2 + cell], 1);
            }
        }
    }
}

// exclusive scan of cnt[98304] -> startm[98304]; single block of 1024
__global__ __launch_bounds__(1024) void scan_kernel(
    const int* __restrict__ cnt, int* __restrict__ startm)
{
    __shared__ int sums[1024];
    const int PER = (NB*3*G2) / 1024; // 96
    int t = threadIdx.x;
    int base = t * PER;
    int s = 0;
    for (int i = 0; i < PER; i++) s += cnt[base + i];
    sums[t] = s;
    __syncthreads();
    for (int off = 1; off < 1024; off <<= 1){
        int v = (t >= off) ? sums[t - off] : 0;
        __syncthreads();
        sums[t] += v;
        __syncthreads();
    }
    int excl = (t == 0) ? 0 : sums[t - 1];
    for (int i = 0; i < PER; i++){
        int c = cnt[base + i];
        startm[base + i] = excl;
        excl += c;
    }
}

// bin point ids per cell; mutates startm (start -> end)
__global__ __launch_bounds__(256) void fill_kernel(
    const float* __restrict__ feats, const float* __restrict__ bounds,
    int* __restrict__ startm, int* __restrict__ plist)
{
    int g = blockIdx.x * 256 + threadIdx.x; // over NB*NPTS
    if (g >= NB*NPTS) return;
    int b = g / NPTS, pt = g % NPTS;
    const float* f = feats + (size_t)g*CC;
    float c3[3];
    #pragma unroll
    for (int a = 0; a < 3; a++){
        float lo = bounds[2*a], hi = bounds[2*a+1];
        float tn = __fmul_rn(2.0f, __fsub_rn(f[a], lo));
        c3[a] = __fsub_rn(__fdiv_rn(tn, __fsub_rn(hi, lo)), 1.0f);
    }
    #pragma unroll
    for (int pl = 0; pl < 3; pl++){
        float a = (pl == 2) ? c3[1] : c3[0];
        float bb = (pl == 0) ? c3[1] : c3[2];
        float ua = __fmul_rn(__fadd_rn(__fmul_rn(a, 0.5f), 0.5f), (float)(GG-1));
        float ub = __fmul_rn(__fadd_rn(__fmul_rn(bb,0.5f), 0.5f), (float)(GG-1));
        int gx = (int)ua; gx = gx < 0 ? 0 : (gx > GG-1 ? GG-1 : gx);
        int gy = (int)ub; gy = gy < 0 ? 0 : (gy > GG-1 ? GG-1 : gy);
        int cellg = (b*3 + pl)*G2 + gx*GG + gy;
        int pos = atomicAdd(&startm[cellg], 1);
        plist[pos] = pt;
    }
}

// one WAVE per (bp, cell): max-prepass (replaces smax atomics), then
// vectorized ushort4 V gather. No LDS, no barriers, no atomics.
__global__ __launch_bounds__(256) void gather_kernel(
    const int* __restrict__ plist, const int* __restrict__ startm,
    const int* __restrict__ cnt, const float* __restrict__ s_in,
    const unsigned short* __restrict__ V, float* __restrict__ out)
{
    int lane = threadIdx.x & 63;
    int cellg = blockIdx.x * 4 + (threadIdx.x >> 6);   // bp*G2 + cell
    int bp = cellg >> 14;
    int b = bp / 3;
    int h = lane >> 4;                                  // head of channels 4l..4l+3

    int end = startm[cellg];
    int n = cnt[cellg];
    int begin = end - n;

    const unsigned short* Vb = V + (size_t)b*NPTS*CC;
    const float* sb = s_in + (size_t)bp*NPTS*HH;

    // ---- prepass: per-head max over this cell's points ----
    float m0 = -INFINITY, m1 = -INFINITY, m2 = -INFINITY, m3 = -INFINITY;
    for (int chunk = begin; chunk < end; chunk += 64){
        int i = chunk + lane;
        if (i < end){
            int p = plist[i];
            float4 sv = *reinterpret_cast<const float4*>(sb + (size_t)p*HH);
            m0 = fmaxf(m0, sv.x); m1 = fmaxf(m1, sv.y);
            m2 = fmaxf(m2, sv.z); m3 = fmaxf(m3, sv.w);
        }
    }
    #pragma unroll
    for (int off = 32; off; off >>= 1){
        m0 = fmaxf(m0, __shfl_xor(m0, off));
        m1 = fmaxf(m1, __shfl_xor(m1, off));
        m2 = fmaxf(m2, __shfl_xor(m2, off));
        m3 = fmaxf(m3, __shfl_xor(m3, off));
    }
    float smh = (h == 0) ? m0 : (h == 1) ? m1 : (h == 2) ? m2 : m3;

    // ---- main pass ----
    float ax = 0.f, ay = 0.f, az = 0.f, aw = 0.f, den = 0.f;
    for (int chunk = begin; chunk < end; chunk += 64){
        int m = min(64, end - chunk);
        int pid = (lane < m) ? plist[chunk + lane] : 0;
        int j = 0;
        for (; j + 4 <= m; j += 4){
            int p0 = __shfl(pid, j  ), p1 = __shfl(pid, j+1);
            int p2 = __shfl(pid, j+2), p3 = __shfl(pid, j+3);
            float e0 = expf(sb[(size_t)p0*HH + h] - smh);
            float e1 = expf(sb[(size_t)p1*HH + h] - smh);
            float e2 = expf(sb[(size_t)p2*HH + h] - smh);
            float e3 = expf(sb[(size_t)p3*HH + h] - smh);
            ushort4 v0 = reinterpret_cast<const ushort4*>(Vb + (size_t)p0*CC)[lane];
            ushort4 v1 = reinterpret_cast<const ushort4*>(Vb + (size_t)p1*CC)[lane];
            ushort4 v2 = reinterpret_cast<const ushort4*>(Vb + (size_t)p2*CC)[lane];
            ushort4 v3 = reinterpret_cast<const ushort4*>(Vb + (size_t)p3*CC)[lane];
            ax = fmaf(e0, bfval(v0.x), ax); ay = fmaf(e0, bfval(v0.y), ay);
            az = fmaf(e0, bfval(v0.z), az); aw = fmaf(e0, bfval(v0.w), aw);
            ax = fmaf(e1, bfval(v1.x), ax); ay = fmaf(e1, bfval(v1.y), ay);
            az = fmaf(e1, bfval(v1.z), az); aw = fmaf(e1, bfval(v1.w), aw);
            ax = fmaf(e2, bfval(v2.x), ax); ay = fmaf(e2, bfval(v2.y), ay);
            az = fmaf(e2, bfval(v2.z), az); aw = fmaf(e2, bfval(v2.w), aw);
            ax = fmaf(e3, bfval(v3.x), ax); ay = fmaf(e3, bfval(v3.y), ay);
            az = fmaf(e3, bfval(v3.z), az); aw = fmaf(e3, bfval(v3.w), aw);
            den += (e0 + e1) + (e2 + e3);
        }
        for (; j < m; ++j){
            int p0 = __shfl(pid, j);
            float e0 = expf(sb[(size_t)p0*HH + h] - smh);
            ushort4 v0 = reinterpret_cast<const ushort4*>(Vb + (size_t)p0*CC)[lane];
            ax = fmaf(e0, bfval(v0.x), ax); ay = fmaf(e0, bfval(v0.y), ay);
            az = fmaf(e0, bfval(v0.z), az); aw = fmaf(e0, bfval(v0.w), aw);
            den += e0;
        }
    }
    float d = fmaxf(den, 1e-30f);
    float4 o = make_float4(ax/d, ay/d, az/d, aw/d);
    reinterpret_cast<float4*>(out + (size_t)cellg*CC)[lane] = o;
}

extern "C" void kernel_launch(void* const* d_in, const int* in_sizes, int n_in,
                              void* d_out, int out_size, void* d_ws, size_t ws_size,
                              hipStream_t stream)
{
    const float* feats  = (const float*)d_in[0];
    const float* bounds = (const float*)d_in[1];
    const float* qxy = (const float*)d_in[2];
    const float* qxz = (const float*)d_in[3];
    const float* qyz = (const float*)d_in[4];
    const float* Wk  = (const float*)d_in[5];
    const float* kb  = (const float*)d_in[6];
    const float* Wv  = (const float*)d_in[7];
    const float* vb  = (const float*)d_in[8];
    const float* lng = (const float*)d_in[9];
    const float* lnb = (const float*)d_in[10];

    char* ws = (char*)d_ws;
    float* qT            = (float*)(ws);                      //  50,331,648
    unsigned short* B2   = (unsigned short*)(ws + 50331648);  //     786,432
    float* bias_comb     = (float*)(ws + 51118080);           //       2,048
    unsigned short* Vbuf = (unsigned short*)(ws + 51120128);  // 102,400,000
    float* s_buf         = (float*)(ws + 153520128);          //   9,600,000
    int* cnt             = (int*)(ws + 163120128);            //     393,216
    int* startm          = (int*)(ws + 163513344);            //     393,216
    int* plist           = (int*)(ws + 163906560);            //   2,400,000
    if (ws_size < 166306560ull) return;

    hipMemsetAsync(cnt, 0, (size_t)NB*3*G2*sizeof(int), stream);
    prep_b2_kernel<<<512, 256, 0, stream>>>(Wk, Wv, kb, vb, B2, bias_comb);
    transpose_q_kernel<<<3072, 256, 0, stream>>>(qxy, qxz, qyz, qT);
    point_kernel<<<6250, 256, 0, stream>>>(feats, bounds, B2, bias_comb,
                                           lng, lnb, qT, Vbuf, s_buf, cnt);
    scan_kernel<<<1, 1024, 0, stream>>>(cnt, startm);
    fill_kernel<<<(NB*NPTS + 255)/256, 256, 0, stream>>>(feats, bounds, startm, plist);
    gather_kernel<<<24576, 256, 0, stream>>>(plist, startm, cnt, s_buf,
                                             Vbuf, (float*)d_out);
}

// Round 13
// 1217.069 us; speedup vs baseline: 1.1891x; 1.1891x over previous
//
#include <hip/hip_runtime.h>
#include <hip/hip_bf16.h>

#define GG 128
#define G2 (GG*GG)
#define CC 256
#define HH 4
#define NPTS 100000
#define NB 2
#define LN_EPS 1e-5f
#define CHUNK 256

typedef __attribute__((ext_vector_type(8))) short short8v;
typedef __attribute__((ext_vector_type(4))) float float4v;

// ---- bf16 helpers (RNE round, bit-level) ----
__device__ __forceinline__ unsigned short bfround(float x){
    unsigned u = __float_as_uint(x);
    return (unsigned short)((u + 0x7FFFu + ((u >> 16) & 1u)) >> 16);
}
__device__ __forceinline__ float bfval(unsigned short h){
    return __uint_as_float(((unsigned)h) << 16);
}

// B2[n][k] bf16, n in [0,512): n<256 -> Wk row n, else Wv row n-256.
// k in [0,256): w_hi ; [256,512): w_lo ; [512,768): w_hi (pairs A''=[hi|hi|lo])
__global__ __launch_bounds__(256) void prep_b2_kernel(
    const float* __restrict__ Wk, const float* __restrict__ Wv,
    const float* __restrict__ kb, const float* __restrict__ vb,
    unsigned short* __restrict__ B2, float* __restrict__ bias_comb)
{
    int n = blockIdx.x;
    int t = threadIdx.x;
    const float* src = (n < 256) ? (Wk + (size_t)n*CC) : (Wv + (size_t)(n-256)*CC);
    float w = src[t];
    unsigned short h = bfround(w);
    unsigned short l = bfround(w - bfval(h));
    unsigned short* row = B2 + (size_t)n*768;
    row[t] = h;
    row[256 + t] = l;
    row[512 + t] = h;
    if (t == 0) bias_comb[n] = (n < 256) ? kb[n] : vb[n-256];
}

// q (C, G2)  ->  qT[plane][cell][c]
__global__ __launch_bounds__(256) void transpose_q_kernel(
    const float* __restrict__ qxy, const float* __restrict__ qxz,
    const float* __restrict__ qyz, float* __restrict__ qT)
{
    int blk = blockIdx.x;
    int plane = blk >> 10;
    int rem = blk & 1023;
    int cell0 = (rem >> 2) << 6;
    int c0 = (rem & 3) << 6;
    const float* q = plane == 0 ? qxy : (plane == 1 ? qxz : qyz);
    __shared__ float tile[64][65];
    int tx = threadIdx.x & 63;
    int ty = threadIdx.x >> 6;
    #pragma unroll
    for (int i = ty; i < 64; i += 4)
        tile[i][tx] = q[(size_t)(c0 + i)*G2 + cell0 + tx];
    __syncthreads();
    #pragma unroll
    for (int i = ty; i < 64; i += 4)
        qT[((size_t)plane*G2 + cell0 + i)*CC + c0 + tx] = tile[tx][i];
}

// Fused: coords + LN + split-bf16 MFMA K&V GEMM + lane-parallel s epilogue.
// (R12-exact)
__global__ __launch_bounds__(256, 4) void point_kernel(
    const float* __restrict__ feats, const float* __restrict__ bounds,
    const unsigned short* __restrict__ B2, const float* __restrict__ bias_comb,
    const float* __restrict__ lng, const float* __restrict__ lnb,
    const float* __restrict__ qT,
    unsigned short* __restrict__ Vout, float* __restrict__ s_out,
    int* __restrict__ cnt)
{
    __shared__ __align__(16) char lraw[34176];
    unsigned short* Ahi = (unsigned short*)lraw;
    unsigned short* Alo = (unsigned short*)(lraw + 16896);
    float* K_f = (float*)lraw;
    float* coords_lds = (float*)(lraw + 33792);

    int t = threadIdx.x;
    int lane = t & 63;
    int w = t >> 6;
    long long g0 = (long long)blockIdx.x * 32;               // 32 | NPTS
    int b  = (int)(g0 / NPTS);
    int pt0 = (int)(g0 % NPTS);

    float xr[8][4];
    #pragma unroll
    for (int r = 0; r < 8; r++){
        int p = w*8 + r;
        const float* f = feats + ((size_t)b*NPTS + pt0 + p)*CC;
        xr[r][0] = f[lane];
        xr[r][1] = f[lane + 64];
        xr[r][2] = f[lane + 128];
        xr[r][3] = f[lane + 192];
    }

    float lg0 = lng[lane], lg1 = lng[lane+64], lg2 = lng[lane+128], lg3 = lng[lane+192];
    float lb0 = lnb[lane], lb1 = lnb[lane+64], lb2 = lnb[lane+128], lb3 = lnb[lane+192];
    #pragma unroll
    for (int r = 0; r < 8; r++){
        int p = w*8 + r;
        float x0 = xr[r][0], x1 = xr[r][1], x2 = xr[r][2], x3 = xr[r][3];
        if (lane < 3){
            float l0 = bounds[2*lane], h0 = bounds[2*lane+1];
            float tnum = __fmul_rn(2.0f, __fsub_rn(x0, l0));
            float cv = __fsub_rn(__fdiv_rn(tnum, __fsub_rn(h0, l0)), 1.0f);
            x0 = cv;
            coords_lds[p*3 + lane] = cv;
        }
        float s1 = x0 + x1 + x2 + x3;
        float s2 = x0*x0 + x1*x1 + x2*x2 + x3*x3;
        #pragma unroll
        for (int off = 32; off; off >>= 1){
            s1 += __shfl_xor(s1, off);
            s2 += __shfl_xor(s2, off);
        }
        float mu = s1 * (1.0f/CC);
        float var = s2 * (1.0f/CC) - mu*mu;
        float rs = rsqrtf(var + LN_EPS);

        float f0 = (x0 - mu)*rs*lg0 + lb0;
        float f1 = (x1 - mu)*rs*lg1 + lb1;
        float f2 = (x2 - mu)*rs*lg2 + lb2;
        float f3 = (x3 - mu)*rs*lg3 + lb3;
        unsigned short h0 = bfround(f0), h1 = bfround(f1);
        unsigned short h2 = bfround(f2), h3 = bfround(f3);
        Ahi[p*264 + lane      ] = h0;  Alo[p*264 + lane      ] = bfround(f0 - bfval(h0));
        Ahi[p*264 + lane +  64] = h1;  Alo[p*264 + lane +  64] = bfround(f1 - bfval(h1));
        Ahi[p*264 + lane + 128] = h2;  Alo[p*264 + lane + 128] = bfround(f2 - bfval(h2));
        Ahi[p*264 + lane + 192] = h3;  Alo[p*264 + lane + 192] = bfround(f3 - bfval(h3));
    }
    __syncthreads();

    {
        int apt = lane & 15;
        int krow = (lane >> 4) * 8;
        int n0 = w * 128;
        int bcol = n0 + (lane & 15);
        float4v acc0[8], acc1[8];
        #pragma unroll
        for (int ni = 0; ni < 8; ni++){
            float bz = bias_comb[n0 + ni*16 + (lane & 15)];
            acc0[ni][0]=bz; acc0[ni][1]=bz; acc0[ni][2]=bz; acc0[ni][3]=bz;
            acc1[ni][0]=bz; acc1[ni][1]=bz; acc1[ni][2]=bz; acc1[ni][3]=bz;
        }
        #pragma unroll 2
        for (int ks = 0; ks < 24; ks++){
            int term = ks >> 3;
            int kk = (ks & 7)*32 + krow;
            int kglob = term*256 + kk;
            const unsigned short* Abase = (term < 2) ? Ahi : Alo;
            short8v a0 = *reinterpret_cast<const short8v*>(Abase + apt*264 + kk);
            short8v a1 = *reinterpret_cast<const short8v*>(Abase + (16+apt)*264 + kk);
            #pragma unroll
            for (int ni = 0; ni < 8; ni++){
                short8v bf = *reinterpret_cast<const short8v*>(
                    B2 + (size_t)(bcol + ni*16)*768 + kglob);
                acc0[ni] = __builtin_amdgcn_mfma_f32_16x16x32_bf16(a0, bf, acc0[ni], 0, 0, 0);
                acc1[ni] = __builtin_amdgcn_mfma_f32_16x16x32_bf16(a1, bf, acc1[ni], 0, 0, 0);
            }
        }
        __syncthreads();
        if (w < 2){
            #pragma unroll
            for (int ni = 0; ni < 8; ni++){
                int ch = n0 + ni*16 + (lane & 15);
                #pragma unroll
                for (int r4 = 0; r4 < 4; r4++){
                    int pt = (lane >> 4)*4 + r4;
                    K_f[pt*260 + ch]        = acc0[ni][r4];
                    K_f[(16 + pt)*260 + ch] = acc1[ni][r4];
                }
            }
        } else {
            #pragma unroll
            for (int ni = 0; ni < 8; ni++){
                int ch = (n0 - 256) + ni*16 + (lane & 15);
                #pragma unroll
                for (int r4 = 0; r4 < 4; r4++){
                    int pt = (lane >> 4)*4 + r4;
                    Vout[((size_t)b*NPTS + pt0 + pt)*CC + ch]        = bfround(acc0[ni][r4]);
                    Vout[((size_t)b*NPTS + pt0 + 16 + pt)*CC + ch]   = bfround(acc1[ni][r4]);
                }
            }
        }
    }
    __syncthreads();

    {
        int grp = lane >> 3;
        int g   = lane & 7;
        int h   = g >> 1;
        int p   = w*8 + grp;
        int pt  = pt0 + p;
        float cx = coords_lds[p*3], cy = coords_lds[p*3+1], cz = coords_lds[p*3+2];

        float4 k4[8];
        {
            const float4* Krow = reinterpret_cast<const float4*>(&K_f[p*260 + g*32]);
            #pragma unroll
            for (int j = 0; j < 8; j++) k4[j] = Krow[j];
        }
        int cells[3];
        #pragma unroll
        for (int pl = 0; pl < 3; pl++){
            float a = (pl == 2) ? cy : cx;
            float bb = (pl == 0) ? cy : cz;
            float ua = __fmul_rn(__fadd_rn(__fmul_rn(a, 0.5f), 0.5f), (float)(GG-1));
            float ub = __fmul_rn(__fadd_rn(__fmul_rn(bb,0.5f), 0.5f), (float)(GG-1));
            int gx = (int)ua; gx = gx < 0 ? 0 : (gx > GG-1 ? GG-1 : gx);
            int gy = (int)ub; gy = gy < 0 ? 0 : (gy > GG-1 ? GG-1 : gy);
            cells[pl] = gx*GG + gy;
        }
        #pragma unroll
        for (int pl = 0; pl < 3; pl++){
            int cell = cells[pl];
            const float4* qrow = reinterpret_cast<const float4*>(
                qT + ((size_t)pl*G2 + cell)*CC + g*32);
            float a0 = 0.f, a1 = 0.f, a2 = 0.f, a3 = 0.f;
            #pragma unroll
            for (int j = 0; j < 8; j++){
                float4 q4 = qrow[j];
                a0 = fmaf(k4[j].x, q4.x, a0);
                a1 = fmaf(k4[j].y, q4.y, a1);
                a2 = fmaf(k4[j].z, q4.z, a2);
                a3 = fmaf(k4[j].w, q4.w, a3);
            }
            float sh = (a0 + a1) + (a2 + a3);
            sh += __shfl_xor(sh, 1);
            if ((lane & 1) == 0){
                int bp = b*3 + pl;
                s_out[((size_t)bp*NPTS + pt)*HH + h] = sh;
                if (g == 0) atomicAdd(&cnt[(size_t)bp*G2 + cell], 1);
            }
        }
    }
}

// exclusive scan of cnt -> startm; emit chunked worklist (CHUNK pts/item)
__global__ __launch_bounds__(1024) void scan_kernel(
    const int* __restrict__ cnt, int* __restrict__ startm,
    int* __restrict__ worklist, int* __restrict__ nwork)
{
    __shared__ int sums[1024];
    __shared__ int sumc[1024];
    const int PER = (NB*3*G2) / 1024; // 96
    int t = threadIdx.x;
    int base = t * PER;
    int s = 0, sc = 0;
    for (int i = 0; i < PER; i++){
        int c = cnt[base + i];
        s += c;
        sc += (c + CHUNK-1) >> 8;
    }
    sums[t] = s; sumc[t] = sc;
    __syncthreads();
    for (int off = 1; off < 1024; off <<= 1){
        int v  = (t >= off) ? sums[t - off] : 0;
        int vc = (t >= off) ? sumc[t - off] : 0;
        __syncthreads();
        sums[t] += v; sumc[t] += vc;
        __syncthreads();
    }
    int excl  = (t == 0) ? 0 : sums[t - 1];
    int exclc = (t == 0) ? 0 : sumc[t - 1];
    for (int i = 0; i < PER; i++){
        int c = cnt[base + i];
        startm[base + i] = excl;
        excl += c;
        int nch = (c + CHUNK-1) >> 8;
        for (int ci = 0; ci < nch; ci++)
            worklist[exclc++] = ((base + i) << 8) | ci;
    }
    if (t == 1023) nwork[0] = exclc;
}

// bin point ids per cell; mutates startm (start -> end)
__global__ __launch_bounds__(256) void fill_kernel(
    const float* __restrict__ feats, const float* __restrict__ bounds,
    int* __restrict__ startm, int* __restrict__ plist)
{
    int g = blockIdx.x * 256 + threadIdx.x; // over NB*NPTS
    if (g >= NB*NPTS) return;
    int b = g / NPTS, pt = g % NPTS;
    const float* f = feats + (size_t)g*CC;
    float c3[3];
    #pragma unroll
    for (int a = 0; a < 3; a++){
        float lo = bounds[2*a], hi = bounds[2*a+1];
        float tn = __fmul_rn(2.0f, __fsub_rn(f[a], lo));
        c3[a] = __fsub_rn(__fdiv_rn(tn, __fsub_rn(hi, lo)), 1.0f);
    }
    #pragma unroll
    for (int pl = 0; pl < 3; pl++){
        float a = (pl == 2) ? c3[1] : c3[0];
        float bb = (pl == 0) ? c3[1] : c3[2];
        float ua = __fmul_rn(__fadd_rn(__fmul_rn(a, 0.5f), 0.5f), (float)(GG-1));
        float ub = __fmul_rn(__fadd_rn(__fmul_rn(bb,0.5f), 0.5f), (float)(GG-1));
        int gx = (int)ua; gx = gx < 0 ? 0 : (gx > GG-1 ? GG-1 : gx);
        int gy = (int)ub; gy = gy < 0 ? 0 : (gy > GG-1 ? GG-1 : gy);
        int cellg = (b*3 + pl)*G2 + gx*GG + gy;
        int pos = atomicAdd(&startm[cellg], 1);
        plist[pos] = pt;
    }
}

// one WAVE per worklist item (cell-chunk of <=CHUNK points).
// Full-cell max prepass (softmax semantics identical); single-chunk cells
// write directly; multi-chunk cells accumulate via atomics + final_norm.
__global__ __launch_bounds__(256) void gather_kernel(
    const int* __restrict__ plist, const int* __restrict__ startm,
    const int* __restrict__ cnt, const float* __restrict__ s_in,
    const unsigned short* __restrict__ V, const int* __restrict__ worklist,
    const int* __restrict__ nwork, float* __restrict__ out,
    float* __restrict__ den_tmp)
{
    int lane = threadIdx.x & 63;
    int wi = blockIdx.x * 4 + (threadIdx.x >> 6);
    if (wi >= nwork[0]) return;
    int item = worklist[wi];
    int cellg = item >> 8;
    int ci = item & 255;
    int bp = cellg >> 14;
    int b = bp / 3;
    int h = lane >> 4;

    int end = startm[cellg];
    int n = cnt[cellg];
    int begin = end - n;

    const unsigned short* Vb = V + (size_t)b*NPTS*CC;
    const float* sb = s_in + (size_t)bp*NPTS*HH;

    // ---- prepass: per-head max over the FULL cell ----
    float m0 = -INFINITY, m1 = -INFINITY, m2 = -INFINITY, m3 = -INFINITY;
    for (int chunk = begin; chunk < end; chunk += 64){
        int i = chunk + lane;
        if (i < end){
            int p = plist[i];
            float4 sv = *reinterpret_cast<const float4*>(sb + (size_t)p*HH);
            m0 = fmaxf(m0, sv.x); m1 = fmaxf(m1, sv.y);
            m2 = fmaxf(m2, sv.z); m3 = fmaxf(m3, sv.w);
        }
    }
    #pragma unroll
    for (int off = 32; off; off >>= 1){
        m0 = fmaxf(m0, __shfl_xor(m0, off));
        m1 = fmaxf(m1, __shfl_xor(m1, off));
        m2 = fmaxf(m2, __shfl_xor(m2, off));
        m3 = fmaxf(m3, __shfl_xor(m3, off));
    }
    float smh = (h == 0) ? m0 : (h == 1) ? m1 : (h == 2) ? m2 : m3;

    // ---- main pass over this chunk ----
    int cb = begin + ci*CHUNK;
    int ce = min(cb + CHUNK, end);
    float ax = 0.f, ay = 0.f, az = 0.f, aw = 0.f, den = 0.f;
    for (int chunk = cb; chunk < ce; chunk += 64){
        int m = min(64, ce - chunk);
        int pid = (lane < m) ? plist[chunk + lane] : 0;
        int j = 0;
        for (; j + 4 <= m; j += 4){
            int p0 = __shfl(pid, j  ), p1 = __shfl(pid, j+1);
            int p2 = __shfl(pid, j+2), p3 = __shfl(pid, j+3);
            float e0 = expf(sb[(size_t)p0*HH + h] - smh);
            float e1 = expf(sb[(size_t)p1*HH + h] - smh);
            float e2 = expf(sb[(size_t)p2*HH + h] - smh);
            float e3 = expf(sb[(size_t)p3*HH + h] - smh);
            ushort4 v0 = reinterpret_cast<const ushort4*>(Vb + (size_t)p0*CC)[lane];
            ushort4 v1 = reinterpret_cast<const ushort4*>(Vb + (size_t)p1*CC)[lane];
            ushort4 v2 = reinterpret_cast<const ushort4*>(Vb + (size_t)p2*CC)[lane];
            ushort4 v3 = reinterpret_cast<const ushort4*>(Vb + (size_t)p3*CC)[lane];
            ax = fmaf(e0, bfval(v0.x), ax); ay = fmaf(e0, bfval(v0.y), ay);
            az = fmaf(e0, bfval(v0.z), az); aw = fmaf(e0, bfval(v0.w), aw);
            ax = fmaf(e1, bfval(v1.x), ax); ay = fmaf(e1, bfval(v1.y), ay);
            az = fmaf(e1, bfval(v1.z), az); aw = fmaf(e1, bfval(v1.w), aw);
            ax = fmaf(e2, bfval(v2.x), ax); ay = fmaf(e2, bfval(v2.y), ay);
            az = fmaf(e2, bfval(v2.z), az); aw = fmaf(e2, bfval(v2.w), aw);
            ax = fmaf(e3, bfval(v3.x), ax); ay = fmaf(e3, bfval(v3.y), ay);
            az = fmaf(e3, bfval(v3.z), az); aw = fmaf(e3, bfval(v3.w), aw);
            den += (e0 + e1) + (e2 + e3);
        }
        for (; j < m; ++j){
            int p0 = __shfl(pid, j);
            float e0 = expf(sb[(size_t)p0*HH + h] - smh);
            ushort4 v0 = reinterpret_cast<const ushort4*>(Vb + (size_t)p0*CC)[lane];
            ax = fmaf(e0, bfval(v0.x), ax); ay = fmaf(e0, bfval(v0.y), ay);
            az = fmaf(e0, bfval(v0.z), az); aw = fmaf(e0, bfval(v0.w), aw);
            den += e0;
        }
    }

    if (n <= CHUNK){
        float d = fmaxf(den, 1e-30f);
        float4 o = make_float4(ax/d, ay/d, az/d, aw/d);
        reinterpret_cast<float4*>(out + (size_t)cellg*CC)[lane] = o;
    } else {
        float* op = out + (size_t)cellg*CC + lane*4;
        atomicAdd(&op[0], ax);
        atomicAdd(&op[1], ay);
        atomicAdd(&op[2], az);
        atomicAdd(&op[3], aw);
        if ((lane & 15) == 0)
            atomicAdd(&den_tmp[(size_t)cellg*HH + h], den);
    }
}

// divide multi-chunk cells by their accumulated denominator
__global__ __launch_bounds__(256) void final_norm_kernel(
    const int* __restrict__ cnt, const float* __restrict__ den_tmp,
    float* __restrict__ out)
{
    int t = threadIdx.x;
    int lane = t & 63;
    int cellg = blockIdx.x * 4 + (t >> 6);
    if (cnt[cellg] <= CHUNK) return;
    float d = fmaxf(den_tmp[(size_t)cellg*HH + (lane >> 4)], 1e-30f);
    float4* o4 = reinterpret_cast<float4*>(out + (size_t)cellg*CC);
    float4 v = o4[lane];
    v.x /= d; v.y /= d; v.z /= d; v.w /= d;
    o4[lane] = v;
}

extern "C" void kernel_launch(void* const* d_in, const int* in_sizes, int n_in,
                              void* d_out, int out_size, void* d_ws, size_t ws_size,
                              hipStream_t stream)
{
    const float* feats  = (const float*)d_in[0];
    const float* bounds = (const float*)d_in[1];
    const float* qxy = (const float*)d_in[2];
    const float* qxz = (const float*)d_in[3];
    const float* qyz = (const float*)d_in[4];
    const float* Wk  = (const float*)d_in[5];
    const float* kb  = (const float*)d_in[6];
    const float* Wv  = (const float*)d_in[7];
    const float* vb  = (const float*)d_in[8];
    const float* lng = (const float*)d_in[9];
    const float* lnb = (const float*)d_in[10];

    char* ws = (char*)d_ws;
    float* qT            = (float*)(ws);                      //  50,331,648
    unsigned short* B2   = (unsigned short*)(ws + 50331648);  //     786,432
    float* bias_comb     = (float*)(ws + 51118080);           //       2,048
    unsigned short* Vbuf = (unsigned short*)(ws + 51120128);  // 102,400,000
    float* s_buf         = (float*)(ws + 153520128);          //   9,600,000
    int* cnt             = (int*)(ws + 163120128);            //     393,216
    int* startm          = (int*)(ws + 163513344);            //     393,216
    int* plist           = (int*)(ws + 163906560);            //   2,400,000
    int* worklist        = (int*)(ws + 166306560);            //     442,368
    float* den_tmp       = (float*)(ws + 166748928);          //   1,572,864
    int* nwork           = (int*)(ws + 168321792);            //           4
    if (ws_size < 168321796ull) return;

    hipMemsetAsync(d_out, 0, (size_t)out_size * sizeof(float), stream);
    hipMemsetAsync(den_tmp, 0, (size_t)NB*3*G2*HH*sizeof(float), stream);
    hipMemsetAsync(cnt, 0, (size_t)NB*3*G2*sizeof(int), stream);
    prep_b2_kernel<<<512, 256, 0, stream>>>(Wk, Wv, kb, vb, B2, bias_comb);
    transpose_q_kernel<<<3072, 256, 0, stream>>>(qxy, qxz, qyz, qT);
    point_kernel<<<6250, 256, 0, stream>>>(feats, bounds, B2, bias_comb,
                                           lng, lnb, qT, Vbuf, s_buf, cnt);
    scan_kernel<<<1, 1024, 0, stream>>>(cnt, startm, worklist, nwork);
    fill_kernel<<<(NB*NPTS + 255)/256, 256, 0, stream>>>(feats, bounds, startm, plist);
    gather_kernel<<<27648, 256, 0, stream>>>(plist, startm, cnt, s_buf,
                                             Vbuf, worklist, nwork,
                                             (float*)d_out, den_tmp);
    final_norm_kernel<<<24576, 256, 0, stream>>>(cnt, den_tmp, (float*)d_out);
}